// Round 1
// baseline (494.607 us; speedup 1.0000x reference)
//
#include <hip/hip_runtime.h>
#include <hip/hip_bf16.h>
#include <cstdint>
#include <math.h>

typedef __attribute__((ext_vector_type(8))) __bf16 bfx8;
typedef __attribute__((ext_vector_type(4))) __bf16 bfx4;
typedef __attribute__((ext_vector_type(4))) float f32x4;

#define EPSN 1e-8f
// 5.0 / ln(2) -> softmax uses exp2
#define SM_SCALE 7.2134752044448170f

__device__ __forceinline__ void gload_lds16(const void* g, void* l) {
    __builtin_amdgcn_global_load_lds(
        (__attribute__((address_space(1))) void*)g,
        (__attribute__((address_space(3))) void*)l,
        16, 0, 0);
}

// ---------------- query norm + bf16 cast + embedding copy ----------------
__global__ __launch_bounds__(256) void qnorm_kernel(
    const float* __restrict__ q, __bf16* __restrict__ qbf,
    float* __restrict__ emb, int D) {
    const int tid = threadIdx.x;
    const size_t roff = (size_t)blockIdx.x * D;
    const float4* qr = (const float4*)(q + roff);
    float4* er = (float4*)(emb + roff);
    const int PASS = D >> 10;  // D/1024, 256 thr * 4 floats
    float4 v[4];
    float ss = 0.f;
    for (int p = 0; p < PASS; ++p) {
        v[p] = qr[p * 256 + tid];
        ss += v[p].x * v[p].x + v[p].y * v[p].y + v[p].z * v[p].z + v[p].w * v[p].w;
    }
    for (int o = 32; o; o >>= 1) ss += __shfl_xor(ss, o);
    __shared__ float sred[4];
    if ((tid & 63) == 0) sred[tid >> 6] = ss;
    __syncthreads();
    float tot = sred[0] + sred[1] + sred[2] + sred[3];
    float inv = 1.f / fmaxf(sqrtf(tot), EPSN);
    for (int p = 0; p < PASS; ++p) {
        er[p * 256 + tid] = v[p];
        bfx4 o4 = {(__bf16)(v[p].x * inv), (__bf16)(v[p].y * inv),
                   (__bf16)(v[p].z * inv), (__bf16)(v[p].w * inv)};
        *(bfx4*)(qbf + roff + (size_t)(p * 256 + tid) * 4) = o4;
    }
}

// ---------------- prototype norm + cast, fc_w cast, zero pad rows ----------------
__global__ __launch_bounds__(256) void pnorm_kernel(
    const float* __restrict__ P, const float* __restrict__ W,
    __bf16* __restrict__ Pn, __bf16* __restrict__ Wb,
    int C, int D) {
    const int c = blockIdx.x;  // 0..CP-1
    const int tid = threadIdx.x;
    const int PASS = D >> 10;
    if (c >= C) {
        bfx4 z = {(__bf16)0.f, (__bf16)0.f, (__bf16)0.f, (__bf16)0.f};
        for (int p = 0; p < PASS; ++p) {
            size_t e = (size_t)c * D + (size_t)(p * 256 + tid) * 4;
            *(bfx4*)(Pn + e) = z;
            *(bfx4*)(Wb + e) = z;
        }
        return;
    }
    const float4* pr = (const float4*)(P + (size_t)c * D);
    float4 v[4];
    float ss = 0.f;
    for (int p = 0; p < PASS; ++p) {
        v[p] = pr[p * 256 + tid];
        ss += v[p].x * v[p].x + v[p].y * v[p].y + v[p].z * v[p].z + v[p].w * v[p].w;
    }
    for (int o = 32; o; o >>= 1) ss += __shfl_xor(ss, o);
    __shared__ float sred[4];
    if ((tid & 63) == 0) sred[tid >> 6] = ss;
    __syncthreads();
    float tot = sred[0] + sred[1] + sred[2] + sred[3];
    float inv = 1.f / fmaxf(sqrtf(tot), EPSN);
    const float4* wr_ = (const float4*)(W + (size_t)c * D);
    for (int p = 0; p < PASS; ++p) {
        size_t e = (size_t)c * D + (size_t)(p * 256 + tid) * 4;
        bfx4 o4 = {(__bf16)(v[p].x * inv), (__bf16)(v[p].y * inv),
                   (__bf16)(v[p].z * inv), (__bf16)(v[p].w * inv)};
        *(bfx4*)(Pn + e) = o4;
        float4 wv = wr_[p * 256 + tid];
        bfx4 w4 = {(__bf16)wv.x, (__bf16)wv.y, (__bf16)wv.z, (__bf16)wv.w};
        *(bfx4*)(Wb + e) = w4;
    }
}

// ---------------- P -> P^T bf16 (with zero pad for c >= C) ----------------
__global__ __launch_bounds__(256) void ptrans_kernel(
    const float* __restrict__ P, __bf16* __restrict__ PT,
    int C, int D, int CP) {
    __shared__ float t[64][65];
    const int d0 = blockIdx.x * 64;
    const int c0 = blockIdx.y * 64;
    const int tid = threadIdx.x;
#pragma unroll
    for (int it = 0; it < 16; ++it) {
        int idx = it * 256 + tid;
        int r = idx >> 6;   // c offset
        int cc = idx & 63;  // d offset
        float v = 0.f;
        if (c0 + r < C) v = P[(size_t)(c0 + r) * D + d0 + cc];
        t[r][cc] = v;
    }
    __syncthreads();
#pragma unroll
    for (int it = 0; it < 16; ++it) {
        int idx = it * 256 + tid;
        int dd = idx >> 6;
        int c = idx & 63;
        PT[(size_t)(d0 + dd) * CP + c0 + c] = (__bf16)t[c][dd];
    }
}

// ---------------- row softmax over C (CP=1024 layout), in place ----------------
__global__ __launch_bounds__(256) void softmax_kernel(
    __bf16* __restrict__ S, int C, int CP) {
    const int tid = threadIdx.x;
    __bf16* row = S + (size_t)blockIdx.x * CP;
    bfx4 v4 = *(const bfx4*)(row + tid * 4);
    const int base = tid * 4;
    float v[4];
    float mx = -INFINITY, rs = 0.f;
#pragma unroll
    for (int j = 0; j < 4; ++j) {
        v[j] = (float)v4[j];
        if (base + j < C) { mx = fmaxf(mx, v[j]); rs += v[j]; }
    }
    for (int o = 32; o; o >>= 1) {
        mx = fmaxf(mx, __shfl_xor(mx, o));
        rs += __shfl_xor(rs, o);
    }
    __shared__ float smx[4], srs[4], sps[4];
    if ((tid & 63) == 0) { smx[tid >> 6] = mx; srs[tid >> 6] = rs; }
    __syncthreads();
    mx = fmaxf(fmaxf(smx[0], smx[1]), fmaxf(smx[2], smx[3]));
    rs = srs[0] + srs[1] + srs[2] + srs[3];
    float p[4], ps = 0.f;
#pragma unroll
    for (int j = 0; j < 4; ++j) {
        p[j] = (base + j < C) ? exp2f((v[j] - mx) * SM_SCALE) : 0.f;
        ps += p[j];
    }
    for (int o = 32; o; o >>= 1) ps += __shfl_xor(ps, o);
    if ((tid & 63) == 0) sps[tid >> 6] = ps;
    __syncthreads();
    ps = sps[0] + sps[1] + sps[2] + sps[3];
    float inv = (rs != 0.f) ? 1.f / ps : 0.f;  // reference's nonzero mask
    bfx4 o4 = {(__bf16)(p[0] * inv), (__bf16)(p[1] * inv),
               (__bf16)(p[2] * inv), (__bf16)(p[3] * inv)};
    *(bfx4*)(row + tid * 4) = o4;
}

// ---------------- NT bf16 GEMM, 128x128 tile, BK=32, 4 waves ----------------
// MODE 0: out bf16 = acc                      (ldout = N stride of out)
// MODE 1: out bf16 = acc + aux[gr*ldout+gc]   (aux fp32, same layout)
// MODE 2: out f32  = acc + aux[gc], write only gc < ldout (ldout = valid N = out ld)
template <int MODE>
__global__ __launch_bounds__(256) void gemm_nt(
    const __bf16* __restrict__ A, const __bf16* __restrict__ B,
    int M, int N, int K,
    void* __restrict__ out, const float* __restrict__ aux, int ldout) {
    __shared__ __bf16 As[128 * 32];
    __shared__ __bf16 Bs[128 * 32];
    const int tid = threadIdx.x;
    const int lane = tid & 63, wid = tid >> 6;
    const int wr = wid >> 1, wc = wid & 1;
    const int fr = lane & 15, fq = lane >> 4;
    const int m0 = blockIdx.y * 128, n0 = blockIdx.x * 128;

    // staging geometry: 8KB per tile = 256 thr * 16B * 2
    const int flat0 = tid * 16;
    const int r0 = flat0 >> 6, c0e = (flat0 & 63) >> 1;
    const int flat1 = flat0 + 4096;
    const int r1 = flat1 >> 6, c1e = (flat1 & 63) >> 1;

    f32x4 acc[4][4] = {};

    for (int kt = 0; kt < K; kt += 32) {
        __syncthreads();
        gload_lds16(A + (size_t)(m0 + r0) * K + kt + c0e, (char*)As + flat0);
        gload_lds16(A + (size_t)(m0 + r1) * K + kt + c1e, (char*)As + flat1);
        gload_lds16(B + (size_t)(n0 + r0) * K + kt + c0e, (char*)Bs + flat0);
        gload_lds16(B + (size_t)(n0 + r1) * K + kt + c1e, (char*)Bs + flat1);
        __syncthreads();
        bfx8 af[4], bfv[4];
#pragma unroll
        for (int m = 0; m < 4; ++m)
            af[m] = *(const bfx8*)(As + (wr * 64 + m * 16 + fr) * 32 + fq * 8);
#pragma unroll
        for (int n = 0; n < 4; ++n)
            bfv[n] = *(const bfx8*)(Bs + (wc * 64 + n * 16 + fr) * 32 + fq * 8);
#pragma unroll
        for (int m = 0; m < 4; ++m)
#pragma unroll
            for (int n = 0; n < 4; ++n)
                acc[m][n] = __builtin_amdgcn_mfma_f32_16x16x32_bf16(
                    af[m], bfv[n], acc[m][n], 0, 0, 0);
    }

#pragma unroll
    for (int m = 0; m < 4; ++m) {
        const int grb = m0 + wr * 64 + m * 16 + fq * 4;
#pragma unroll
        for (int n = 0; n < 4; ++n) {
            const int gc = n0 + wc * 64 + n * 16 + fr;
#pragma unroll
            for (int j = 0; j < 4; ++j) {
                const int gr = grb + j;
                const float va = acc[m][n][j];
                if (MODE == 0) {
                    ((__bf16*)out)[(size_t)gr * ldout + gc] = (__bf16)va;
                } else if (MODE == 1) {
                    const float qv = aux[(size_t)gr * ldout + gc];
                    ((__bf16*)out)[(size_t)gr * ldout + gc] = (__bf16)(va + qv);
                } else {
                    if (gc < ldout)
                        ((float*)out)[(size_t)gr * ldout + gc] = va + aux[gc];
                }
            }
        }
    }
}

extern "C" void kernel_launch(void* const* d_in, const int* in_sizes, int n_in,
                              void* d_out, int out_size, void* d_ws, size_t ws_size,
                              hipStream_t stream) {
    const float* q  = (const float*)d_in[0];
    const float* pr = (const float*)d_in[1];
    const float* fw = (const float*)d_in[2];
    const float* fb = (const float*)d_in[3];
    const int C = in_sizes[3];              // 1000
    const int D = in_sizes[1] / C;          // 2048
    const int B = in_sizes[0] / D;          // 16384
    const int CP = (C + 127) & ~127;        // 1024

    float* logits = (float*)d_out;
    float* emb = logits + (size_t)B * C;

    char* w = (char*)d_ws;
    __bf16* Qb = (__bf16*)w; w += (size_t)B * D * 2;    // 67.1 MB
    __bf16* Pn = (__bf16*)w; w += (size_t)CP * D * 2;   // 4.2 MB
    __bf16* PT = (__bf16*)w; w += (size_t)D * CP * 2;   // 4.2 MB
    __bf16* Wb = (__bf16*)w; w += (size_t)CP * D * 2;   // 4.2 MB
    __bf16* Sb = (__bf16*)w; w += (size_t)B * CP * 2;   // 33.6 MB
    __bf16* Xb = Qb;  // alias: Qb dead after gemm<0>

    qnorm_kernel<<<B, 256, 0, stream>>>(q, Qb, emb, D);
    pnorm_kernel<<<CP, 256, 0, stream>>>(pr, fw, Pn, Wb, C, D);
    ptrans_kernel<<<dim3(D / 64, CP / 64), 256, 0, stream>>>(pr, PT, C, D, CP);
    // cos = Qn @ Pn^T  -> Sb [B, CP] bf16
    gemm_nt<0><<<dim3(CP / 128, B / 128), 256, 0, stream>>>(
        Qb, Pn, B, CP, D, (void*)Sb, nullptr, CP);
    softmax_kernel<<<B, 256, 0, stream>>>(Sb, C, CP);
    // X = attn @ P + q  -> Xb [B, D] bf16
    gemm_nt<1><<<dim3(D / 128, B / 128), 256, 0, stream>>>(
        Sb, PT, B, D, CP, (void*)Xb, q, D);
    // logits = X @ W^T + b -> [B, C] f32
    gemm_nt<2><<<dim3(CP / 128, B / 128), 256, 0, stream>>>(
        Xb, Wb, B, CP, D, (void*)logits, fb, C);
}

// Round 3
// 380.341 us; speedup vs baseline: 1.3004x; 1.3004x over previous
//
#include <hip/hip_runtime.h>
#include <hip/hip_bf16.h>
#include <cstdint>
#include <math.h>

typedef __attribute__((ext_vector_type(8))) __bf16 bfx8;
typedef __attribute__((ext_vector_type(4))) __bf16 bfx4;
typedef __attribute__((ext_vector_type(4))) float f32x4;

#define EPSN 1e-8f
// 5.0 / ln(2) -> softmax uses exp2
#define SM_SCALE 7.2134752044448170f

__device__ __forceinline__ void gload_lds16(const void* g, void* l) {
    __builtin_amdgcn_global_load_lds(
        (__attribute__((address_space(1))) void*)g,
        (__attribute__((address_space(3))) void*)l,
        16, 0, 0);
}

// ---------------- query norm + bf16 cast + embedding copy ----------------
__global__ __launch_bounds__(256) void qnorm_kernel(
    const float* __restrict__ q, __bf16* __restrict__ qbf,
    float* __restrict__ emb, int D) {
    const int tid = threadIdx.x;
    const size_t roff = (size_t)blockIdx.x * D;
    const float4* qr = (const float4*)(q + roff);
    float4* er = (float4*)(emb + roff);
    const int PASS = D >> 10;  // D/1024, 256 thr * 4 floats
    float4 v[4];
    float ss = 0.f;
    for (int p = 0; p < PASS; ++p) {
        v[p] = qr[p * 256 + tid];
        ss += v[p].x * v[p].x + v[p].y * v[p].y + v[p].z * v[p].z + v[p].w * v[p].w;
    }
    for (int o = 32; o; o >>= 1) ss += __shfl_xor(ss, o);
    __shared__ float sred[4];
    if ((tid & 63) == 0) sred[tid >> 6] = ss;
    __syncthreads();
    float tot = sred[0] + sred[1] + sred[2] + sred[3];
    float inv = 1.f / fmaxf(sqrtf(tot), EPSN);
    for (int p = 0; p < PASS; ++p) {
        er[p * 256 + tid] = v[p];
        bfx4 o4 = {(__bf16)(v[p].x * inv), (__bf16)(v[p].y * inv),
                   (__bf16)(v[p].z * inv), (__bf16)(v[p].w * inv)};
        *(bfx4*)(qbf + roff + (size_t)(p * 256 + tid) * 4) = o4;
    }
}

// ---------------- prototype norm + cast, fc_w cast, zero pad rows ----------------
__global__ __launch_bounds__(256) void pnorm_kernel(
    const float* __restrict__ P, const float* __restrict__ W,
    __bf16* __restrict__ Pn, __bf16* __restrict__ Wb,
    int C, int D) {
    const int c = blockIdx.x;  // 0..CP-1
    const int tid = threadIdx.x;
    const int PASS = D >> 10;
    if (c >= C) {
        bfx4 z = {(__bf16)0.f, (__bf16)0.f, (__bf16)0.f, (__bf16)0.f};
        for (int p = 0; p < PASS; ++p) {
            size_t e = (size_t)c * D + (size_t)(p * 256 + tid) * 4;
            *(bfx4*)(Pn + e) = z;
            *(bfx4*)(Wb + e) = z;
        }
        return;
    }
    const float4* pr = (const float4*)(P + (size_t)c * D);
    float4 v[4];
    float ss = 0.f;
    for (int p = 0; p < PASS; ++p) {
        v[p] = pr[p * 256 + tid];
        ss += v[p].x * v[p].x + v[p].y * v[p].y + v[p].z * v[p].z + v[p].w * v[p].w;
    }
    for (int o = 32; o; o >>= 1) ss += __shfl_xor(ss, o);
    __shared__ float sred[4];
    if ((tid & 63) == 0) sred[tid >> 6] = ss;
    __syncthreads();
    float tot = sred[0] + sred[1] + sred[2] + sred[3];
    float inv = 1.f / fmaxf(sqrtf(tot), EPSN);
    const float4* wr_ = (const float4*)(W + (size_t)c * D);
    for (int p = 0; p < PASS; ++p) {
        size_t e = (size_t)c * D + (size_t)(p * 256 + tid) * 4;
        bfx4 o4 = {(__bf16)(v[p].x * inv), (__bf16)(v[p].y * inv),
                   (__bf16)(v[p].z * inv), (__bf16)(v[p].w * inv)};
        *(bfx4*)(Pn + e) = o4;
        float4 wv = wr_[p * 256 + tid];
        bfx4 w4 = {(__bf16)wv.x, (__bf16)wv.y, (__bf16)wv.z, (__bf16)wv.w};
        *(bfx4*)(Wb + e) = w4;
    }
}

// ---------------- P -> P^T bf16 (with zero pad for c >= C) ----------------
__global__ __launch_bounds__(256) void ptrans_kernel(
    const float* __restrict__ P, __bf16* __restrict__ PT,
    int C, int D, int CP) {
    __shared__ float t[64][65];
    const int d0 = blockIdx.x * 64;
    const int c0 = blockIdx.y * 64;
    const int tid = threadIdx.x;
#pragma unroll
    for (int it = 0; it < 16; ++it) {
        int idx = it * 256 + tid;
        int r = idx >> 6;   // c offset
        int cc = idx & 63;  // d offset
        float v = 0.f;
        if (c0 + r < C) v = P[(size_t)(c0 + r) * D + d0 + cc];
        t[r][cc] = v;
    }
    __syncthreads();
#pragma unroll
    for (int it = 0; it < 16; ++it) {
        int idx = it * 256 + tid;
        int dd = idx >> 6;
        int c = idx & 63;
        PT[(size_t)(d0 + dd) * CP + c0 + c] = (__bf16)t[c][dd];
    }
}

// ---------------- row softmax over C (CP=1024 layout), in place ----------------
__global__ __launch_bounds__(256) void softmax_kernel(
    __bf16* __restrict__ S, int C, int CP) {
    const int tid = threadIdx.x;
    __bf16* row = S + (size_t)blockIdx.x * CP;
    bfx4 v4 = *(const bfx4*)(row + tid * 4);
    const int base = tid * 4;
    float v[4];
    float mx = -INFINITY, rs = 0.f;
#pragma unroll
    for (int j = 0; j < 4; ++j) {
        v[j] = (float)v4[j];
        if (base + j < C) { mx = fmaxf(mx, v[j]); rs += v[j]; }
    }
    for (int o = 32; o; o >>= 1) {
        mx = fmaxf(mx, __shfl_xor(mx, o));
        rs += __shfl_xor(rs, o);
    }
    __shared__ float smx[4], srs[4], sps[4];
    if ((tid & 63) == 0) { smx[tid >> 6] = mx; srs[tid >> 6] = rs; }
    __syncthreads();
    mx = fmaxf(fmaxf(smx[0], smx[1]), fmaxf(smx[2], smx[3]));
    rs = srs[0] + srs[1] + srs[2] + srs[3];
    float p[4], ps = 0.f;
#pragma unroll
    for (int j = 0; j < 4; ++j) {
        p[j] = (base + j < C) ? exp2f((v[j] - mx) * SM_SCALE) : 0.f;
        ps += p[j];
    }
    for (int o = 32; o; o >>= 1) ps += __shfl_xor(ps, o);
    if ((tid & 63) == 0) sps[tid >> 6] = ps;
    __syncthreads();
    ps = sps[0] + sps[1] + sps[2] + sps[3];
    float inv = (rs != 0.f) ? 1.f / ps : 0.f;  // reference's nonzero mask
    bfx4 o4 = {(__bf16)(p[0] * inv), (__bf16)(p[1] * inv),
               (__bf16)(p[2] * inv), (__bf16)(p[3] * inv)};
    *(bfx4*)(row + tid * 4) = o4;
}

// ================= 256x256 8-phase NT bf16 GEMM (BK=64, 8 waves) =================
// LDS: A[2 buf][16384 elem] at [0,32768), B[2 buf] at [32768,65536).
// Each 16KB buf-half = 8 subtile-rows x 2 subtile-cols of [16][32]-elem subtiles
// (1024B) with st_16x32 swizzle: elem_col ^= 16 when (row&8).
// Phase Q=(qm,qn) reads A-half qm, B-half qn.  Last-read phases:
//   A-h0 -> 1, B-h0 -> 2, A-h1 -> 3, B-h1 -> 3.
// Stage slots during tile T (safe: same-buf halves staged only AFTER their last
// reader's end-barrier):
//   (T,0): A-h1 of T+1 (s=4T+6, other buf)   (T,1): B-h1 of T+1 (s=4T+7, other buf)
//   (T,2): A-h0 of T+2 (s=4T+8, cur buf, last read ph1)
//   (T,3): B-h0 of T+2 (s=4T+9, cur buf, last read ph2) + vmcnt(4)
// vmcnt(4) at each tile end => stages through (T,1) landed = all of tile T+1;
// the two T+2 stages stay in flight across the barrier (counted, never 0).
// MODE 0: out bf16 = acc           MODE 1: out bf16 = acc + aux[r*ldout+c]
// MODE 2: out f32  = acc + aux[c], only c < ldout
template <int MODE>
__global__ __launch_bounds__(512, 2) void gemm8p(
    const __bf16* __restrict__ A, const __bf16* __restrict__ B_,
    int K, int NT, int nbxl, int nwg,
    void* __restrict__ out, const float* __restrict__ aux, int ldout) {
    __shared__ __bf16 lds[65536];  // 128 KiB

    const int tid = threadIdx.x;
    const int lane = tid & 63, wid = tid >> 6;
    const int wr = wid >> 2, wc = wid & 3;
    const int fr = lane & 15, fq = lane >> 4;
    const int wr4 = wr * 4, wc2 = wc * 2;
    // fragment LDS offset within a subtile (elements), swizzled
    const int frs = fr * 32 + ((fq * 8) ^ ((fr & 8) << 1));

    // XCD-aware bijective block swizzle (nwg % 8 == 0)
    const int nbx = 1 << nbxl;
    const int lin = blockIdx.y * nbx + blockIdx.x;
    const int swz = (lin & 7) * (nwg >> 3) + (lin >> 3);
    const int bm0 = (swz >> nbxl) * 256;
    const int bn0 = (swz & (nbx - 1)) * 256;

    // staging source mapping (inverse swizzle), per thread, issues i=0,1
    int row0, col0, row1, col1;
    {
        int Le = tid * 8;
        int st = Le >> 9, w = Le & 511;
        row0 = (st >> 1) * 16 + (w >> 5);
        col0 = (st & 1) * 32 + ((w & 31) ^ ((w >> 4) & 16));
        Le = tid * 8 + 4096;
        st = Le >> 9; w = Le & 511;
        row1 = (st >> 1) * 16 + (w >> 5);
        col1 = (st & 1) * 32 + ((w & 31) ^ ((w >> 4) & 16));
    }
    const __bf16* Ap = A + (size_t)bm0 * K;
    const __bf16* Bp = B_ + (size_t)bn0 * K;

    auto STAGE = [&](int s) {
        const int t = s >> 2, h = s & 3;
        const int kt = t << 6;
        const int be = ((t & 1) << 14) + ((h >> 1) << 13);  // buf*16384 + half*8192
        const __bf16* src = (h & 1) ? Bp : Ap;
        src += (size_t)((h >> 1) * 128) * K + kt;
        __bf16* d = (h & 1) ? (lds + 32768 + be) : (lds + be);
        gload_lds16(src + (size_t)row0 * K + col0, d + tid * 8);
        gload_lds16(src + (size_t)row1 * K + col1, d + tid * 8 + 4096);
    };

    f32x4 acc[4][4][2] = {};  // [quadrant][m][n]

#define PHASE(Q, T, SS, WMODE) do {                                            \
    const int qm_ = (Q) >> 1, qn_ = (Q) & 1;                                   \
    const int bufe_ = ((T) & 1) << 14;                                         \
    bfx8 af_[4][2], bb_[2][2];                                                 \
    _Pragma("unroll") for (int m_ = 0; m_ < 4; ++m_)                           \
      _Pragma("unroll") for (int ks_ = 0; ks_ < 2; ++ks_)                      \
        af_[m_][ks_] = *(const bfx8*)&lds[bufe_ +                              \
            (((qm_ * 8 + wr4 + m_) * 2 + ks_) << 9) + frs];                    \
    _Pragma("unroll") for (int n_ = 0; n_ < 2; ++n_)                           \
      _Pragma("unroll") for (int ks_ = 0; ks_ < 2; ++ks_)                      \
        bb_[n_][ks_] = *(const bfx8*)&lds[32768 + bufe_ +                      \
            (((qn_ * 8 + wc2 + n_) * 2 + ks_) << 9) + frs];                    \
    if ((SS) >= 0) STAGE(SS);                                                  \
    __builtin_amdgcn_s_barrier();                                              \
    asm volatile("s_waitcnt lgkmcnt(0)" ::: "memory");                         \
    __builtin_amdgcn_s_setprio(1);                                             \
    _Pragma("unroll") for (int ks_ = 0; ks_ < 2; ++ks_)                        \
      _Pragma("unroll") for (int m_ = 0; m_ < 4; ++m_)                         \
        _Pragma("unroll") for (int n_ = 0; n_ < 2; ++n_)                       \
          acc[Q][m_][n_] = __builtin_amdgcn_mfma_f32_16x16x32_bf16(            \
              af_[m_][ks_], bb_[n_][ks_], acc[Q][m_][n_], 0, 0, 0);            \
    __builtin_amdgcn_s_setprio(0);                                             \
    if ((WMODE) == 1) asm volatile("s_waitcnt vmcnt(4)" ::: "memory");         \
    else if ((WMODE) == 2) asm volatile("s_waitcnt vmcnt(0)" ::: "memory");    \
    __builtin_amdgcn_s_barrier();                                              \
} while (0)

    // prologue: stage halves 0..5 (tile0 full + tile1 A-h0,B-h0), land tile0
#pragma unroll
    for (int s = 0; s < 6; ++s) STAGE(s);
    asm volatile("s_waitcnt vmcnt(4)" ::: "memory");
    __builtin_amdgcn_s_barrier();

    int T = 0;
    for (; T <= NT - 3; ++T) {
        PHASE(0, T, 4 * T + 6, 0);
        PHASE(1, T, 4 * T + 7, 0);
        PHASE(2, T, 4 * T + 8, 0);
        PHASE(3, T, 4 * T + 9, 1);
    }
    // T == NT-2: stage last two halves of tile NT-1, then full drain
    PHASE(0, T, 4 * T + 6, 0);
    PHASE(1, T, 4 * T + 7, 0);
    PHASE(2, T, -1, 0);
    PHASE(3, T, -1, 2);
    ++T;  // T == NT-1
    PHASE(0, T, -1, 0);
    PHASE(1, T, -1, 0);
    PHASE(2, T, -1, 0);
    PHASE(3, T, -1, 0);
#undef PHASE

    // epilogue: C write. gr = bm0+qm*128+wr*64+m*16+fq*4+j ; gc = bn0+qn*128+wc*32+n*16+fr
#pragma unroll
    for (int q = 0; q < 4; ++q) {
        const int qm_ = q >> 1, qn_ = q & 1;
#pragma unroll
        for (int m = 0; m < 4; ++m) {
            const int grb = bm0 + qm_ * 128 + wr * 64 + m * 16 + fq * 4;
#pragma unroll
            for (int n = 0; n < 2; ++n) {
                const int gc = bn0 + qn_ * 128 + wc * 32 + n * 16 + fr;
#pragma unroll
                for (int j = 0; j < 4; ++j) {
                    const int gr = grb + j;
                    const float va = acc[q][m][n][j];
                    if (MODE == 0) {
                        ((__bf16*)out)[(size_t)gr * ldout + gc] = (__bf16)va;
                    } else if (MODE == 1) {
                        ((__bf16*)out)[(size_t)gr * ldout + gc] =
                            (__bf16)(va + aux[(size_t)gr * ldout + gc]);
                    } else {
                        if (gc < ldout)
                            ((float*)out)[(size_t)gr * ldout + gc] = va + aux[gc];
                    }
                }
            }
        }
    }
}

extern "C" void kernel_launch(void* const* d_in, const int* in_sizes, int n_in,
                              void* d_out, int out_size, void* d_ws, size_t ws_size,
                              hipStream_t stream) {
    const float* q  = (const float*)d_in[0];
    const float* pr = (const float*)d_in[1];
    const float* fw = (const float*)d_in[2];
    const float* fb = (const float*)d_in[3];
    const int C = in_sizes[3];              // 1000
    const int D = in_sizes[1] / C;          // 2048
    const int B = in_sizes[0] / D;          // 16384
    const int CP = (C + 127) & ~127;        // 1024

    float* logits = (float*)d_out;
    float* emb = logits + (size_t)B * C;

    char* w = (char*)d_ws;
    __bf16* Qb = (__bf16*)w; w += (size_t)B * D * 2;    // 67.1 MB
    __bf16* Pn = (__bf16*)w; w += (size_t)CP * D * 2;   // 4.2 MB
    __bf16* PT = (__bf16*)w; w += (size_t)D * CP * 2;   // 4.2 MB
    __bf16* Wb = (__bf16*)w; w += (size_t)CP * D * 2;   // 4.2 MB
    __bf16* Sb = (__bf16*)w; w += (size_t)B * CP * 2;   // 33.6 MB
    __bf16* Xb = Qb;  // alias: Qb dead after gemm<0>

    qnorm_kernel<<<B, 256, 0, stream>>>(q, Qb, emb, D);
    pnorm_kernel<<<CP, 256, 0, stream>>>(pr, fw, Pn, Wb, C, D);
    ptrans_kernel<<<dim3(D / 64, CP / 64), 256, 0, stream>>>(pr, PT, C, D, CP);

    // cos = Qn @ Pn^T  -> Sb [B, CP] bf16
    {
        const int nbx = CP / 256, nby = B / 256;  // 4 x 64
        gemm8p<0><<<dim3(nbx, nby), 512, 0, stream>>>(
            Qb, Pn, D, D / 64, 2, nbx * nby, (void*)Sb, nullptr, CP);
    }
    softmax_kernel<<<B, 256, 0, stream>>>(Sb, C, CP);
    // X = attn @ P + q  -> Xb [B, D] bf16
    {
        const int nbx = D / 256, nby = B / 256;  // 8 x 64
        gemm8p<1><<<dim3(nbx, nby), 512, 0, stream>>>(
            Sb, PT, CP, CP / 64, 3, nbx * nby, (void*)Xb, q, D);
    }
    // logits = X @ W^T + b -> [B, C] f32
    {
        const int nbx = CP / 256, nby = B / 256;  // 4 x 64
        gemm8p<2><<<dim3(nbx, nby), 512, 0, stream>>>(
            Xb, Wb, D, D / 64, 2, nbx * nby, (void*)logits, fb, C);
    }
}